// Round 1
// 2600.494 us; speedup vs baseline: 1.0094x; 1.0094x over previous
//
#include <hip/hip_runtime.h>

// dense_baens: out[n,e] = sum_d x[n,d] * U[n,d,e] + bias[n,0,e]
// N=2048, D1=512, D2=512, fp32. U = 2.147 GB streamed once -> memory-bound,
// roofline ~345 us at 6.3 TB/s for the kernel dispatch.
//
// R1 theory: the 128-thr-block baseline keeps 2048 resident blocks, each
// streaming a private 1 MiB slab -> device footprint = 2048 positions
// spread 1 MiB apart over the full 2 GiB. DRAM rows get their chunks read
// microseconds apart (same stream, 64 KB of progress apart) -> multiple
// activations per row, bank thrash; measured ~1.75 TB/s (kernel ~1235 us).
// Fix: 1024-thread block (16 waves) per sample; thread (r=t>>7, c=t&127)
// accumulates d = r mod 8 over float4 column-quad c, so each step the
// block reads rows 8i..8i+7 = 16 KB CONTIGUOUS, sweeping the slab
// sequentially. 256-512 compact sliding windows instead of 2048 scattered
// 2 KB positions -> copy-like DRAM behavior. Same coalescing (1 KB/wave),
// same waves/CU (16), same bytes; d-split folded by a 16 KB LDS tree.

constexpr int N  = 2048;
constexpr int D1 = 512;
constexpr int D2 = 512;

constexpr int THREADS = 1024;       // 16 waves per block
constexpr int CQ = D2 / 4;          // 128 float4 column-quads per row
constexpr int RS = THREADS / CQ;    // 8-way d-split within the block

__global__ __launch_bounds__(THREADS) void baens_gemv_kernel(
    const float* __restrict__ x,
    const float* __restrict__ U,
    const float* __restrict__ bias,
    float* __restrict__ out)
{
    __shared__ float  xs[D1];       // 2 KB: x[n] broadcast source
    __shared__ float4 red[RS][CQ];  // 16 KB: d-split reduction scratch

    const int n = blockIdx.x;
    const int t = threadIdx.x;
    const int c = t & (CQ - 1);     // column quad 0..127
    const int r = t >> 7;           // d-phase 0..7

    // Stage x[n] (512 floats): first 128 threads, float4 each.
    if (t < CQ) {
        reinterpret_cast<float4*>(xs)[t] =
            reinterpret_cast<const float4*>(x + (size_t)n * D1)[t];
    }
    __syncthreads();

    // Thread's base: row r, column quad c of U[n].
    const float4* Up =
        reinterpret_cast<const float4*>(U + (size_t)n * D1 * D2) +
        (size_t)r * CQ + c;

    float4 acc = make_float4(0.f, 0.f, 0.f, 0.f);

    // 64 steps; at step i the 16 waves together read rows i*8..i*8+7
    // = 16 KB contiguous. Unroll 8 -> 8 float4 loads in flight/lane
    // (131 KB in flight per CU at 16 waves; need ~9 KB for 900-cyc lat).
    #pragma unroll 8
    for (int i = 0; i < D1 / RS; ++i) {
        const float xv = xs[i * RS + r];              // LDS broadcast
        const float4 u = Up[(size_t)i * (RS * CQ)];   // coalesced 16B/lane
        acc.x += xv * u.x;
        acc.y += xv * u.y;
        acc.z += xv * u.z;
        acc.w += xv * u.w;
    }

    // Fold the 8 d-phase partials per column quad: LDS tree.
    red[r][c] = acc;
    __syncthreads();
    if (r < 4) {
        float4 a = red[r][c];
        const float4 b = red[r + 4][c];
        a.x += b.x; a.y += b.y; a.z += b.z; a.w += b.w;
        red[r][c] = a;
    }
    __syncthreads();
    if (r < 2) {
        float4 a = red[r][c];
        const float4 b = red[r + 2][c];
        a.x += b.x; a.y += b.y; a.z += b.z; a.w += b.w;
        red[r][c] = a;
    }
    __syncthreads();
    if (r == 0) {
        const float4 a = red[0][c];
        const float4 b = red[1][c];
        const float4 bi =
            reinterpret_cast<const float4*>(bias + (size_t)n * D2)[c];
        float4 o;
        o.x = a.x + b.x + bi.x;
        o.y = a.y + b.y + bi.y;
        o.z = a.z + b.z + bi.z;
        o.w = a.w + b.w + bi.w;
        reinterpret_cast<float4*>(out + (size_t)n * D2)[c] = o;
    }
}

extern "C" void kernel_launch(void* const* d_in, const int* in_sizes, int n_in,
                              void* d_out, int out_size, void* d_ws, size_t ws_size,
                              hipStream_t stream) {
    const float* x    = (const float*)d_in[0];  // (N, D1)
    const float* U    = (const float*)d_in[1];  // (N, D1, D2)
    const float* bias = (const float*)d_in[2];  // (N, 1, D2)
    float* out        = (float*)d_out;          // (N, D2)

    baens_gemv_kernel<<<N, THREADS, 0, stream>>>(x, U, bias, out);
}